// Round 14
// baseline (651.265 us; speedup 1.0000x reference)
//
#include <hip/hip_runtime.h>
#include <cstddef>

#define HDIM 2048
#define NE 64
#define TOPK 4
#define BM2 32

// ---------- transpose+scale pre-pass: wt[k][e] = w[e][k] * scale[k] ----------
__global__ __launch_bounds__(256) void transpose_w_kernel(
    const float* __restrict__ w, const float* __restrict__ scale,
    float* __restrict__ wt)
{
    __shared__ float Wl[64][65];
    const int tid = threadIdx.x;
    const int k0 = blockIdx.x * 64;          // grid = HDIM/64 = 32
    #pragma unroll
    for (int q = 0; q < 4; q++) {
        int f = tid + 256 * q;
        int e = f >> 4;
        int k4 = (f & 15) * 4;
        float4 v = *(const float4*)(w + (size_t)e * HDIM + k0 + k4);
        Wl[e][k4 + 0] = v.x; Wl[e][k4 + 1] = v.y;
        Wl[e][k4 + 2] = v.z; Wl[e][k4 + 3] = v.w;
    }
    __syncthreads();
    #pragma unroll
    for (int q = 0; q < 4; q++) {
        int f = tid + 256 * q;
        int k = f >> 4;
        int e4 = (f & 15) * 4;
        float s = scale[k0 + k];
        float4 v;
        v.x = Wl[e4 + 0][k] * s; v.y = Wl[e4 + 1][k] * s;
        v.z = Wl[e4 + 2][k] * s; v.w = Wl[e4 + 3][k] * s;
        *(float4*)(wt + (size_t)(k0 + k) * NE + e4) = v;
    }
}

// ---------- GEMM: A staged via global_load_lds DMA into per-wave double panes ----------
// No ds_writes, no lgkmcnt drains; one counted vmcnt(16) per chunk. Pane layout is
// 16B-unit column-major: word(t,q) = 256q + 4t -> gll instr n stages seg q=n for all
// 64 tokens (lane = token, full cache line per chunk), and Ai b128 reads at rows
// 8i+tr hit banks 4*tr: conflict-free. ssq folded into the FMA stream.
template<int KS>
__global__ __launch_bounds__(512, 1) void gemm14_kernel(
    const float* __restrict__ x, const float* __restrict__ wt,
    float* __restrict__ sp0,     // partial scores ks=0 (probs region)
    float* __restrict__ spws,    // partial scores ks=1..KS-1
    float* __restrict__ sq,      // [KS][tokens] partial ssq
    int tokens)
{
    constexpr int KR = HDIM / KS;      // 256 @ KS=8
    constexpr int NCH = KR / 16;       // 16-k chunks
    __shared__ float P[8][2][1024];    // [wave][pane][64 tok x 16 k] = 64 KB

    const int tid = threadIdx.x;
    const int wu = __builtin_amdgcn_readfirstlane(tid >> 6);   // uniform wave id
    const int l = tid & 63;
    const int ks = blockIdx.x & (KS - 1);
    const int tile = blockIdx.x / KS;
    const int tokw0 = tile * 512 + wu * 64;
    const int k0 = ks * KR;

    float* p0 = P[wu][0];
    float* p1 = P[wu][1];

    const int tr = l & 7;              // token-octet (compute)
    const int ec = l >> 3;             // expert-octet (compute)

    const float* xg = x + (size_t)(tokw0 + l) * HDIM + k0;   // lane = token (gll source)
    const float* wb = wt + (size_t)k0 * NE + 8 * ec;

    float acc[8][8];
    #pragma unroll
    for (int i = 0; i < 8; i++)
        #pragma unroll
        for (int j = 0; j < 8; j++) acc[i][j] = 0.f;
    float ssqp[8];
    #pragma unroll
    for (int i = 0; i < 8; i++) ssqp[i] = 0.f;

    float4 B0[4][2], B1[4][2];

#define GLLC(pane, c) { \
        __builtin_amdgcn_sched_barrier(0); \
        _Pragma("unroll") \
        for (int n = 0; n < 4; ++n) \
            __builtin_amdgcn_global_load_lds( \
                (const __attribute__((address_space(1))) void*)(xg + (c) * 16 + 4 * n), \
                (__attribute__((address_space(3))) void*)((pane) + 256 * n), 16, 0, 0); \
        __builtin_amdgcn_sched_barrier(0); }
#define LDA(Ai, pane, kq) { _Pragma("unroll") \
        for (int i = 0; i < 8; ++i) \
            Ai[i] = *(const float4*)((pane) + 256 * (kq) + 4 * (8 * i + tr)); }
#define SSQB(Ai) { _Pragma("unroll") \
        for (int i = 0; i < 8; ++i) { \
            ssqp[i] = fmaf(Ai[i].x, Ai[i].x, ssqp[i]); \
            ssqp[i] = fmaf(Ai[i].y, Ai[i].y, ssqp[i]); \
            ssqp[i] = fmaf(Ai[i].z, Ai[i].z, ssqp[i]); \
            ssqp[i] = fmaf(Ai[i].w, Ai[i].w, ssqp[i]); } }
#define LOADB(B, R) { _Pragma("unroll") \
        for (int kk = 0; kk < 4; ++kk) { \
            B[kk][0] = *(const float4*)(wb + (size_t)((R) + kk) * NE); \
            B[kk][1] = *(const float4*)(wb + (size_t)((R) + kk) * NE + 4); } }
#define FMABLK(Ai, B) { _Pragma("unroll") \
        for (int kk = 0; kk < 4; ++kk) { \
            _Pragma("unroll") \
            for (int h = 0; h < 2; ++h) { \
                float4 Bv = B[kk][h]; \
                _Pragma("unroll") \
                for (int i = 0; i < 8; ++i) { \
                    float av = (kk == 0) ? Ai[i].x : (kk == 1) ? Ai[i].y \
                             : (kk == 2) ? Ai[i].z : Ai[i].w; \
                    acc[i][4*h + 0] = fmaf(av, Bv.x, acc[i][4*h + 0]); \
                    acc[i][4*h + 1] = fmaf(av, Bv.y, acc[i][4*h + 1]); \
                    acc[i][4*h + 2] = fmaf(av, Bv.z, acc[i][4*h + 2]); \
                    acc[i][4*h + 3] = fmaf(av, Bv.w, acc[i][4*h + 3]); \
                } \
            } \
        } }

    // prologue: stage chunks 0,1; preload B for chunk 0 (B0=even kq, B1=odd kq)
    GLLC(p0, 0);
    LOADB(B0, 0);
    LOADB(B1, 4);
    GLLC(p1, 1);

    for (int c = 0; c < NCH; ++c) {
        float* pc = (c & 1) ? p1 : p0;
        const int R = 16 * c;
        // pane pc's 4 gll ops are at least 21 vmem ops old -> vmcnt(16) guarantees them
        asm volatile("s_waitcnt vmcnt(16)" ::: "memory");
        __builtin_amdgcn_sched_barrier(0);

        float4 Ai0[8], Ai1[8];
        LDA(Ai0, pc, 0);
        LDA(Ai1, pc, 1);
        FMABLK(Ai0, B0);                       // kq0
        SSQB(Ai0);
        LOADB(B0, R + 8);                      // (c, kq2)
        LDA(Ai0, pc, 2);
        FMABLK(Ai1, B1);                       // kq1
        SSQB(Ai1);
        LOADB(B1, R + 12);                     // (c, kq3)
        LDA(Ai1, pc, 3);
        FMABLK(Ai0, B0);                       // kq2
        SSQB(Ai0);
        if (c + 1 < NCH) LOADB(B0, R + 16);    // (c+1, kq0)
        FMABLK(Ai1, B1);                       // kq3
        SSQB(Ai1);
        if (c + 1 < NCH) LOADB(B1, R + 20);    // (c+1, kq1)
        if (c + 2 < NCH) GLLC(pc, c + 2);      // refill the pane just consumed
    }
#undef GLLC
#undef LDA
#undef SSQB
#undef LOADB
#undef FMABLK

    // ssq: each (8i+tr) row is replicated across the 8 ec lanes; ec==0 writes
    if (ec == 0) {
        #pragma unroll
        for (int i = 0; i < 8; ++i)
            sq[(size_t)ks * tokens + tokw0 + 8 * i + tr] = ssqp[i];
    }

    float* sp = (ks == 0) ? sp0 : (spws + (size_t)(ks - 1) * tokens * NE);
    #pragma unroll
    for (int i = 0; i < 8; ++i) {      // token 8i+tr, experts 8ec..8ec+7
        size_t off = (size_t)(tokw0 + 8 * i + tr) * NE + 8 * ec;
        float4 v0 = {acc[i][0], acc[i][1], acc[i][2], acc[i][3]};
        float4 v1 = {acc[i][4], acc[i][5], acc[i][6], acc[i][7]};
        *(float4*)(sp + off) = v0;
        *(float4*)(sp + off + 4) = v1;
    }
}

// ---------- finisher: tree-sum KS partials, rmsnorm, softmax, top-4 ----------
template<int KS>
__global__ __launch_bounds__(256) void finish14_kernel(
    const float* __restrict__ sp0, const float* __restrict__ spws,
    const float* __restrict__ sq, const float* __restrict__ pes,
    float* __restrict__ probs, float* __restrict__ tkw, float* __restrict__ tki,
    int tokens)
{
    __shared__ float Sl[BM2 * 65];
    __shared__ float Pl[BM2 * 65];
    __shared__ float FN[BM2];
    __shared__ float RS[BM2];

    const int tid = threadIdx.x;
    const int tok0 = blockIdx.x * BM2;

    if (tid < BM2) {
        float q[KS];
        #pragma unroll
        for (int i = 0; i < KS; i++) q[i] = sq[(size_t)i * tokens + tok0 + tid];
        #pragma unroll
        for (int st = 1; st < KS; st <<= 1)
            #pragma unroll
            for (int i = 0; i < KS; i += 2 * st) q[i] += q[i + st];
        FN[tid] = rsqrtf(q[0] * (1.0f / HDIM) + 1e-6f) * 0.022097086912079612f;
    }
    __syncthreads();

    #pragma unroll
    for (int qq = 0; qq < 2; qq++) {
        int f = tid + 256 * qq;
        int m = f >> 4;
        int e4 = f & 15;
        float4 t[KS];
        t[0] = ((const float4*)sp0)[(size_t)(tok0 + m) * (NE / 4) + e4];
        #pragma unroll
        for (int i = 1; i < KS; i++)
            t[i] = ((const float4*)(spws + (size_t)(i - 1) * tokens * NE))
                       [(size_t)(tok0 + m) * (NE / 4) + e4];
        #pragma unroll
        for (int st = 1; st < KS; st <<= 1)
            #pragma unroll
            for (int i = 0; i < KS; i += 2 * st) {
                t[i].x += t[i + st].x; t[i].y += t[i + st].y;
                t[i].z += t[i + st].z; t[i].w += t[i + st].w;
            }
        float fn = FN[m];
        int base = m * 65 + e4 * 4;
        Sl[base + 0] = t[0].x * fn; Sl[base + 1] = t[0].y * fn;
        Sl[base + 2] = t[0].z * fn; Sl[base + 3] = t[0].w * fn;
    }
    __syncthreads();

    if (tid < BM2) {
        const int m = tid;
        float mx = -3.0e38f;
        for (int e = 0; e < NE; e++) mx = fmaxf(mx, Sl[m * 65 + e]);
        float sum = 0.f;
        for (int e = 0; e < NE; e++) {
            float p = __expf(Sl[m * 65 + e] - mx);
            Pl[m * 65 + e] = p;
            sum += p;
        }
        RS[m] = 1.0f / sum;
    }
    __syncthreads();

    #pragma unroll
    for (int qq = 0; qq < 2; qq++) {
        int f = tid + 256 * qq;
        int m = f >> 4;
        int e0 = (f & 15) * 4;
        float rs = RS[m];
        float4 pv;
        pv.x = Pl[m * 65 + e0 + 0] * rs;
        pv.y = Pl[m * 65 + e0 + 1] * rs;
        pv.z = Pl[m * 65 + e0 + 2] * rs;
        pv.w = Pl[m * 65 + e0 + 3] * rs;
        *(float4*)&probs[(size_t)(tok0 + m) * NE + e0] = pv;
    }

    if (tid < BM2) {                   // destructive top-4, lowest-index ties
        const int m = tid;
        float wv[TOPK]; int idx[TOPK];
        float wsum = 0.f;
        #pragma unroll
        for (int kk = 0; kk < TOPK; ++kk) {
            float best = -3.0e38f; int bi = 0;
            for (int e = 0; e < NE; e++) {
                float v = Sl[m * 65 + e];
                if (v > best) { best = v; bi = e; }
            }
            Sl[m * 65 + bi] = -3.4e38f;
            float p = Pl[m * 65 + bi];
            wv[kk] = p; idx[kk] = bi; wsum += p;
        }
        float inv = 1.0f / wsum;
        size_t ob = (size_t)(tok0 + m) * TOPK;
        #pragma unroll
        for (int kk = 0; kk < TOPK; kk++) {
            tkw[ob + kk] = wv[kk] * inv * pes[idx[kk]];
            tki[ob + kk] = (float)idx[kk];   // harness reads flat buffer as float32
        }
    }
}

extern "C" void kernel_launch(void* const* d_in, const int* in_sizes, int n_in,
                              void* d_out, int out_size, void* d_ws, size_t ws_size,
                              hipStream_t stream) {
    const float* x     = (const float*)d_in[0];
    const float* w     = (const float*)d_in[1];
    const float* scale = (const float*)d_in[2];
    const float* pes   = (const float*)d_in[3];
    const int tokens = in_sizes[0] / HDIM;      // 16384

    float* probs = (float*)d_out;
    float* tkw   = probs + (size_t)tokens * NE;
    float* tki   = tkw + (size_t)tokens * TOPK;

    const size_t wtN = (size_t)HDIM * NE;
    const size_t spN = (size_t)tokens * NE;
    const size_t need8 = (wtN + 7 * spN + (size_t)8 * tokens) * sizeof(float);
    const int KS = (ws_size >= need8) ? 8 : 4;

    float* wt   = (float*)d_ws;
    float* spws = wt + wtN;
    float* sq   = spws + (size_t)(KS - 1) * spN;
    float* sp0  = probs;                        // overwritten by finisher

    transpose_w_kernel<<<HDIM / 64, 256, 0, stream>>>(w, scale, wt);

    const int grid1 = (tokens / 512) * KS;      // 256 @ KS=8 -> 1 block/CU
    if (KS == 8)
        gemm14_kernel<8><<<grid1, 512, 0, stream>>>(x, wt, sp0, spws, sq, tokens);
    else
        gemm14_kernel<4><<<grid1, 512, 0, stream>>>(x, wt, sp0, spws, sq, tokens);

    const int grid2 = tokens / BM2;             // 512
    if (KS == 8)
        finish14_kernel<8><<<grid2, 256, 0, stream>>>(sp0, spws, sq, pes, probs, tkw, tki, tokens);
    else
        finish14_kernel<4><<<grid2, 256, 0, stream>>>(sp0, spws, sq, pes, probs, tkw, tki, tokens);
}

// Round 15
// 96.237 us; speedup vs baseline: 6.7673x; 6.7673x over previous
//
#include <hip/hip_runtime.h>
#include <cstddef>

#define HDIM 2048
#define NE 64
#define TOPK 4
#define BM2 32

typedef float v2f __attribute__((ext_vector_type(2)));

__device__ __forceinline__ v2f pkfma(v2f a, v2f b, v2f c) {
#if __has_builtin(__builtin_elementwise_fma)
    return __builtin_elementwise_fma(a, b, c);   // -> v_pk_fma_f32
#else
    v2f d = c;
    asm("v_pk_fma_f32 %0, %1, %2, %0" : "+v"(d) : "v"(a), "v"(b));
    return d;
#endif
}

// ---------- transpose+scale pre-pass: wt[k][e] = w[e][k] * scale[k] ----------
__global__ __launch_bounds__(256) void transpose_w_kernel(
    const float* __restrict__ w, const float* __restrict__ scale,
    float* __restrict__ wt)
{
    __shared__ float Wl[64][65];
    const int tid = threadIdx.x;
    const int k0 = blockIdx.x * 64;          // grid = HDIM/64 = 32
    #pragma unroll
    for (int q = 0; q < 4; q++) {
        int f = tid + 256 * q;
        int e = f >> 4;
        int k4 = (f & 15) * 4;
        float4 v = *(const float4*)(w + (size_t)e * HDIM + k0 + k4);
        Wl[e][k4 + 0] = v.x; Wl[e][k4 + 1] = v.y;
        Wl[e][k4 + 2] = v.z; Wl[e][k4 + 3] = v.w;
    }
    __syncthreads();
    #pragma unroll
    for (int q = 0; q < 4; q++) {
        int f = tid + 256 * q;
        int k = f >> 4;
        int e4 = (f & 15) * 4;
        float s = scale[k0 + k];
        float4 v;
        v.x = Wl[e4 + 0][k] * s; v.y = Wl[e4 + 1][k] * s;
        v.z = Wl[e4 + 2][k] * s; v.w = Wl[e4 + 3][k] * s;
        *(float4*)(wt + (size_t)(k0 + k) * NE + e4) = v;
    }
}

// ---------- GEMM: r13 structure verbatim, inner loop in PACKED fp32 ----------
// Peak fp32 on CDNA4 needs v_pk_fma_f32 (157 TF); scalar v_fma caps ~103 TF.
// acc pairs span adjacent experts; per-element accumulation chains unchanged
// -> bitwise-identical to the passing scalar version.
template<int KS>
__global__ __launch_bounds__(512, 1) void gemm15_kernel(
    const float* __restrict__ x, const float* __restrict__ wt,
    float* __restrict__ sp0,     // partial scores ks=0 (probs region)
    float* __restrict__ spws,    // partial scores ks=1..KS-1
    float* __restrict__ sq,      // [KS][tokens] partial ssq
    int tokens)
{
    constexpr int KR = HDIM / KS;      // 256 @ KS=8
    constexpr int NCH = KR / 8;        // 8-k chunks
    __shared__ float As_all[8][64][12];  // per-wave A pane (24 KB)

    const int tid = threadIdx.x;
    const int w = tid >> 6;
    const int l = tid & 63;
    const int ks = blockIdx.x & (KS - 1);
    const int tile = blockIdx.x / KS;
    const int tokw0 = tile * 512 + w * 64;
    const int k0 = ks * KR;

    float (*As)[12] = As_all[w];

    const int tr = l & 7;              // token-octet index (compute)
    const int ec = l >> 3;             // expert-octet (compute)

    // A staging: lane -> (tokens atok, atok+32; k-half ah)  [r7-verified]
    const int atok = l >> 1;
    const int ah = l & 1;
    const int aswz = ah ^ ((l >> 4) & 1);
    const float* xa0 = x + (size_t)(tokw0 + atok) * HDIM + k0 + 4 * ah;
    const float* xa1 = xa0 + (size_t)32 * HDIM;

    // B base: experts 8ec..8ec+7, k advances by rows of NE
    const float* wb = wt + (size_t)k0 * NE + 8 * ec;

    v2f acc2[8][4];                    // [token i][expert-pair jj] = experts (2jj,2jj+1)
    #pragma unroll
    for (int i = 0; i < 8; i++)
        #pragma unroll
        for (int jj = 0; jj < 4; jj++) acc2[i][jj] = (v2f){0.f, 0.f};
    float ssq0 = 0.f, ssq1 = 0.f;

    float4 pa0, pa1;
    float4 B0[4][2], B1[4][2];

#define LOADA(c) { pa0 = *(const float4*)(xa0 + (c) * 8); \
                   pa1 = *(const float4*)(xa1 + (c) * 8); }
#define STOREA() { \
        *(float4*)&As[atok][4 * aswz] = pa0; \
        *(float4*)&As[32 + atok][4 * aswz] = pa1; \
        ssq0 += pa0.x*pa0.x + pa0.y*pa0.y + pa0.z*pa0.z + pa0.w*pa0.w; \
        ssq1 += pa1.x*pa1.x + pa1.y*pa1.y + pa1.z*pa1.z + pa1.w*pa1.w; }
#define LOADB(B, roff) { _Pragma("unroll") \
        for (int kk = 0; kk < 4; ++kk) { \
            B[kk][0] = *(const float4*)(wb + (size_t)((roff) + kk) * NE); \
            B[kk][1] = *(const float4*)(wb + (size_t)((roff) + kk) * NE + 4); } }
#define FMABLK(Ai, B) { _Pragma("unroll") \
        for (int kk = 0; kk < 4; ++kk) { \
            _Pragma("unroll") \
            for (int i = 0; i < 8; ++i) { \
                float av = (kk == 0) ? Ai[i].x : (kk == 1) ? Ai[i].y \
                         : (kk == 2) ? Ai[i].z : Ai[i].w; \
                v2f a2 = {av, av}; \
                const v2f* b0p = (const v2f*)&B[kk][0]; \
                const v2f* b1p = (const v2f*)&B[kk][1]; \
                acc2[i][0] = pkfma(a2, b0p[0], acc2[i][0]); \
                acc2[i][1] = pkfma(a2, b0p[1], acc2[i][1]); \
                acc2[i][2] = pkfma(a2, b1p[0], acc2[i][2]); \
                acc2[i][3] = pkfma(a2, b1p[1], acc2[i][3]); \
            } \
        } }

    LOADA(0);
    STOREA();                          // vmcnt wait inserted by compiler
    LOADB(B0, 0);                      // chunk 0, rows 0-3
    LOADB(B1, 4);                      // chunk 0, rows 4-7

    for (int c = 0; c < NCH; ++c) {
        const int r8 = 8 * c;
        if (c + 1 < NCH) LOADA(c + 1);     // next A chunk in flight
        {
            float4 Ai[8];
            #pragma unroll
            for (int i = 0; i < 8; ++i)    // rows 8i+tr: banks tile, no conflict
                Ai[i] = *(const float4*)&As[8 * i + tr][4 * (0 ^ (i & 1))];
            FMABLK(Ai, B0);                // kq0: B0 loaded >=1 FMA-block ago
        }
        if (c + 1 < NCH) LOADB(B0, r8 + 8);    // next chunk rows 0-3
        {
            float4 Ai[8];
            #pragma unroll
            for (int i = 0; i < 8; ++i)
                Ai[i] = *(const float4*)&As[8 * i + tr][4 * (1 ^ (i & 1))];
            FMABLK(Ai, B1);                // kq1
        }
        if (c + 1 < NCH) {
            LOADB(B1, r8 + 12);            // next chunk rows 4-7
            // chunk-c ds_reads must land before pane overwrite (same wave, in order)
            asm volatile("s_waitcnt lgkmcnt(0)" ::: "memory");
            STOREA();
        }
    }
#undef LOADA
#undef STOREA
#undef LOADB
#undef FMABLK

    // ssq: combine the two k-half lanes of each token (lanes 2t, 2t+1)
    ssq0 += __shfl_xor(ssq0, 1, 64);
    ssq1 += __shfl_xor(ssq1, 1, 64);
    if (ah == 0) {
        sq[(size_t)ks * tokens + tokw0 + atok] = ssq0;
        sq[(size_t)ks * tokens + tokw0 + 32 + atok] = ssq1;
    }

    float* sp = (ks == 0) ? sp0 : (spws + (size_t)(ks - 1) * tokens * NE);
    #pragma unroll
    for (int i = 0; i < 8; ++i) {      // token 8i+tr, experts 8ec..8ec+7
        size_t off = (size_t)(tokw0 + 8 * i + tr) * NE + 8 * ec;
        float4 v0 = {acc2[i][0].x, acc2[i][0].y, acc2[i][1].x, acc2[i][1].y};
        float4 v1 = {acc2[i][2].x, acc2[i][2].y, acc2[i][3].x, acc2[i][3].y};
        *(float4*)(sp + off) = v0;
        *(float4*)(sp + off + 4) = v1;
    }
}

// ---------- finisher: tree-sum KS partials, rmsnorm, softmax, top-4 ----------
template<int KS>
__global__ __launch_bounds__(256) void finish15_kernel(
    const float* __restrict__ sp0, const float* __restrict__ spws,
    const float* __restrict__ sq, const float* __restrict__ pes,
    float* __restrict__ probs, float* __restrict__ tkw, float* __restrict__ tki,
    int tokens)
{
    __shared__ float Sl[BM2 * 65];
    __shared__ float Pl[BM2 * 65];
    __shared__ float FN[BM2];
    __shared__ float RS[BM2];

    const int tid = threadIdx.x;
    const int tok0 = blockIdx.x * BM2;

    if (tid < BM2) {
        float q[KS];
        #pragma unroll
        for (int i = 0; i < KS; i++) q[i] = sq[(size_t)i * tokens + tok0 + tid];
        #pragma unroll
        for (int st = 1; st < KS; st <<= 1)
            #pragma unroll
            for (int i = 0; i < KS; i += 2 * st) q[i] += q[i + st];
        FN[tid] = rsqrtf(q[0] * (1.0f / HDIM) + 1e-6f) * 0.022097086912079612f;
    }
    __syncthreads();

    #pragma unroll
    for (int qq = 0; qq < 2; qq++) {
        int f = tid + 256 * qq;
        int m = f >> 4;
        int e4 = f & 15;
        float4 t[KS];
        t[0] = ((const float4*)sp0)[(size_t)(tok0 + m) * (NE / 4) + e4];
        #pragma unroll
        for (int i = 1; i < KS; i++)
            t[i] = ((const float4*)(spws + (size_t)(i - 1) * tokens * NE))
                       [(size_t)(tok0 + m) * (NE / 4) + e4];
        #pragma unroll
        for (int st = 1; st < KS; st <<= 1)
            #pragma unroll
            for (int i = 0; i < KS; i += 2 * st) {
                t[i].x += t[i + st].x; t[i].y += t[i + st].y;
                t[i].z += t[i + st].z; t[i].w += t[i + st].w;
            }
        float fn = FN[m];
        int base = m * 65 + e4 * 4;
        Sl[base + 0] = t[0].x * fn; Sl[base + 1] = t[0].y * fn;
        Sl[base + 2] = t[0].z * fn; Sl[base + 3] = t[0].w * fn;
    }
    __syncthreads();

    if (tid < BM2) {
        const int m = tid;
        float mx = -3.0e38f;
        for (int e = 0; e < NE; e++) mx = fmaxf(mx, Sl[m * 65 + e]);
        float sum = 0.f;
        for (int e = 0; e < NE; e++) {
            float p = __expf(Sl[m * 65 + e] - mx);
            Pl[m * 65 + e] = p;
            sum += p;
        }
        RS[m] = 1.0f / sum;
    }
    __syncthreads();

    #pragma unroll
    for (int qq = 0; qq < 2; qq++) {
        int f = tid + 256 * qq;
        int m = f >> 4;
        int e0 = (f & 15) * 4;
        float rs = RS[m];
        float4 pv;
        pv.x = Pl[m * 65 + e0 + 0] * rs;
        pv.y = Pl[m * 65 + e0 + 1] * rs;
        pv.z = Pl[m * 65 + e0 + 2] * rs;
        pv.w = Pl[m * 65 + e0 + 3] * rs;
        *(float4*)&probs[(size_t)(tok0 + m) * NE + e0] = pv;
    }

    if (tid < BM2) {                   // destructive top-4, lowest-index ties
        const int m = tid;
        float wv[TOPK]; int idx[TOPK];
        float wsum = 0.f;
        #pragma unroll
        for (int kk = 0; kk < TOPK; ++kk) {
            float best = -3.0e38f; int bi = 0;
            for (int e = 0; e < NE; e++) {
                float v = Sl[m * 65 + e];
                if (v > best) { best = v; bi = e; }
            }
            Sl[m * 65 + bi] = -3.4e38f;
            float p = Pl[m * 65 + bi];
            wv[kk] = p; idx[kk] = bi; wsum += p;
        }
        float inv = 1.0f / wsum;
        size_t ob = (size_t)(tok0 + m) * TOPK;
        #pragma unroll
        for (int kk = 0; kk < TOPK; kk++) {
            tkw[ob + kk] = wv[kk] * inv * pes[idx[kk]];
            tki[ob + kk] = (float)idx[kk];   // harness reads flat buffer as float32
        }
    }
}

extern "C" void kernel_launch(void* const* d_in, const int* in_sizes, int n_in,
                              void* d_out, int out_size, void* d_ws, size_t ws_size,
                              hipStream_t stream) {
    const float* x     = (const float*)d_in[0];
    const float* w     = (const float*)d_in[1];
    const float* scale = (const float*)d_in[2];
    const float* pes   = (const float*)d_in[3];
    const int tokens = in_sizes[0] / HDIM;      // 16384

    float* probs = (float*)d_out;
    float* tkw   = probs + (size_t)tokens * NE;
    float* tki   = tkw + (size_t)tokens * TOPK;

    const size_t wtN = (size_t)HDIM * NE;
    const size_t spN = (size_t)tokens * NE;
    const size_t need8 = (wtN + 7 * spN + (size_t)8 * tokens) * sizeof(float);
    const int KS = (ws_size >= need8) ? 8 : 4;

    float* wt   = (float*)d_ws;
    float* spws = wt + wtN;
    float* sq   = spws + (size_t)(KS - 1) * spN;
    float* sp0  = probs;                        // overwritten by finisher

    transpose_w_kernel<<<HDIM / 64, 256, 0, stream>>>(w, scale, wt);

    const int grid1 = (tokens / 512) * KS;      // 256 @ KS=8 -> 1 block/CU
    if (KS == 8)
        gemm15_kernel<8><<<grid1, 512, 0, stream>>>(x, wt, sp0, spws, sq, tokens);
    else
        gemm15_kernel<4><<<grid1, 512, 0, stream>>>(x, wt, sp0, spws, sq, tokens);

    const int grid2 = tokens / BM2;             // 512
    if (KS == 8)
        finish15_kernel<8><<<grid2, 256, 0, stream>>>(sp0, spws, sq, pes, probs, tkw, tki, tokens);
    else
        finish15_kernel<4><<<grid2, 256, 0, stream>>>(sp0, spws, sq, pes, probs, tkw, tki, tokens);
}

// Round 16
// 57.112 us; speedup vs baseline: 11.4032x; 1.6850x over previous
//
#include <hip/hip_runtime.h>
#include <cstddef>

#define HDIM 2048
#define NE 64
#define TOPK 4

typedef short bf16x8 __attribute__((ext_vector_type(8)));
typedef float f32x4 __attribute__((ext_vector_type(4)));

// Exact 3-way bf16 truncation split: a = f(h0) + f(h1) + f(h2) (24 mantissa bits).
__device__ __forceinline__ void split3(float a, unsigned short& h0,
                                       unsigned short& h1, unsigned short& h2) {
    unsigned int u = __float_as_uint(a);
    h0 = (unsigned short)(u >> 16);
    float f0 = __uint_as_float(u & 0xffff0000u);
    float r1 = a - f0;
    unsigned int v = __float_as_uint(r1);
    h1 = (unsigned short)(v >> 16);
    float f1 = __uint_as_float(v & 0xffff0000u);
    float r2 = r1 - f1;
    h2 = (unsigned short)(__float_as_uint(r2) >> 16);
}

// ---------- prepass: B into MFMA fragment layout, 3 bf16 planes ----------
// wtb[plane][s(64)][n(4)][lane(64)][j(8)]: value = split(w[e][k]*scale[k]),
// e = 16n + (lane&15), k = 32s + 8*(lane>>4) + j. plane stride 131072 shorts.
__global__ __launch_bounds__(256) void prep_b_kernel(
    const float* __restrict__ w, const float* __restrict__ scale,
    unsigned short* __restrict__ wtb)
{
    const int s = blockIdx.x;          // 0..63
    const int n = threadIdx.x >> 6;    // 0..3
    const int l = threadIdx.x & 63;
    const int e = 16 * n + (l & 15);
    const int k = 32 * s + 8 * (l >> 4);
    unsigned short h0[8], h1[8], h2[8];
    #pragma unroll
    for (int j = 0; j < 8; ++j) {
        float v = w[(size_t)e * HDIM + k + j] * scale[k + j];
        split3(v, h0[j], h1[j], h2[j]);
    }
    size_t off = ((size_t)s * 4 + n) * 512 + (size_t)l * 8;
    #pragma unroll
    for (int j = 0; j < 8; ++j) {
        wtb[off + j]          = h0[j];
        wtb[131072 + off + j] = h1[j];
        wtb[262144 + off + j] = h2[j];
    }
}

// ---------- fused: MFMA GEMM (split-3 bf16 = fp32-exact) + rmsnorm + softmax + top4 ----------
// Block = 32 tokens, 4 waves: (token-half, K-half). Per wave: 16 tok x 64 exp x 1024 K.
// Hot loop has ZERO LDS: x global->reg (lines consumed exactly once), B frags L1/L2-hot.
__global__ __launch_bounds__(256) void fused_router_kernel(
    const float* __restrict__ x, const unsigned short* __restrict__ wtb,
    const float* __restrict__ pes,
    float* __restrict__ probs, float* __restrict__ tkw, float* __restrict__ tki)
{
    __shared__ float Sl[32 * 65];
    __shared__ float Pl[32 * 65];
    __shared__ float P2[32 * 65];
    __shared__ float SQ2[32];
    __shared__ float FN[32];
    __shared__ float RS[32];

    const int tid = threadIdx.x;
    const int wv = tid >> 6;
    const int l = tid & 63;
    const int th = wv & 1;             // token half: rows 16*th..16*th+15
    const int kh = wv >> 1;            // K half: k in [1024*kh, 1024*kh+1024)
    const int tok0 = blockIdx.x * 32;
    const int m = l & 15;              // A row / B col / fragment non-K index
    const int g = l >> 4;              // k-group

    const float* xr = x + (size_t)(tok0 + 16 * th + m) * HDIM + 1024 * kh + 8 * g;
    const unsigned short* wb = wtb + (size_t)(32 * kh) * 2048 + (size_t)l * 8;

    f32x4 acc[4];
    #pragma unroll
    for (int n = 0; n < 4; ++n) acc[n] = (f32x4){0.f, 0.f, 0.f, 0.f};
    float ssq = 0.f;

    float4 xa = *(const float4*)(xr);
    float4 xb = *(const float4*)(xr + 4);

    for (int s = 0; s < 32; ++s) {
        float4 na = xa, nb = xb;
        if (s + 1 < 32) {              // next kstep's 8 floats in flight under compute
            na = *(const float4*)(xr + 32 * (s + 1));
            nb = *(const float4*)(xr + 32 * (s + 1) + 4);
        }
        float af[8];
        *(float4*)af = xa; *(float4*)(af + 4) = xb;
        unsigned short h0[8], h1[8], h2[8];
        #pragma unroll
        for (int j = 0; j < 8; ++j) {
            split3(af[j], h0[j], h1[j], h2[j]);
            ssq = fmaf(af[j], af[j], ssq);
        }
        bf16x8 a0, a1, a2;
        #pragma unroll
        for (int j = 0; j < 8; ++j) {
            a0[j] = (short)h0[j]; a1[j] = (short)h1[j]; a2[j] = (short)h2[j];
        }
        const unsigned short* bs = wb + (size_t)s * 2048;
        #pragma unroll
        for (int n = 0; n < 4; ++n) {
            bf16x8 b0 = *(const bf16x8*)(bs + n * 512);
            bf16x8 b1 = *(const bf16x8*)(bs + n * 512 + 131072);
            bf16x8 b2 = *(const bf16x8*)(bs + n * 512 + 262144);
            // 6 products >= 2^-16; residual ~2^-23 * |ab| = fp32-class
            acc[n] = __builtin_amdgcn_mfma_f32_16x16x32_bf16(a0, b0, acc[n], 0, 0, 0);
            acc[n] = __builtin_amdgcn_mfma_f32_16x16x32_bf16(a0, b1, acc[n], 0, 0, 0);
            acc[n] = __builtin_amdgcn_mfma_f32_16x16x32_bf16(a1, b0, acc[n], 0, 0, 0);
            acc[n] = __builtin_amdgcn_mfma_f32_16x16x32_bf16(a1, b1, acc[n], 0, 0, 0);
            acc[n] = __builtin_amdgcn_mfma_f32_16x16x32_bf16(a0, b2, acc[n], 0, 0, 0);
            acc[n] = __builtin_amdgcn_mfma_f32_16x16x32_bf16(a2, b0, acc[n], 0, 0, 0);
        }
        xa = na; xb = nb;
    }

    // ssq: combine the 4 k-group lanes of each token (lanes differ in bits 4,5)
    ssq += __shfl_xor(ssq, 16, 64);
    ssq += __shfl_xor(ssq, 32, 64);

    // ---- cross-wave K-combine + fnorm ----
    if (kh == 1) {
        #pragma unroll
        for (int n = 0; n < 4; ++n)
            #pragma unroll
            for (int r = 0; r < 4; ++r)
                P2[(16 * th + 4 * g + r) * 65 + 16 * n + m] = acc[n][r];
        if (l < 16) SQ2[16 * th + l] = ssq;
    }
    __syncthreads();
    if (kh == 0 && l < 16) {
        float st = ssq + SQ2[16 * th + l];
        FN[16 * th + l] = rsqrtf(st * (1.0f / HDIM) + 1e-6f) * 0.022097086912079612f;
    }
    __syncthreads();
    if (kh == 0) {
        #pragma unroll
        for (int n = 0; n < 4; ++n)
            #pragma unroll
            for (int r = 0; r < 4; ++r) {
                int ti = 16 * th + 4 * g + r;   // D row = 4*(lane>>4)+reg [m89-verified]
                Sl[ti * 65 + 16 * n + m] =
                    (acc[n][r] + P2[ti * 65 + 16 * n + m]) * FN[ti];
            }
    }
    __syncthreads();

    // ---- proven epilogue (r13 finisher, 32 tokens, no partials) ----
    if (tid < 32) {
        const int mm = tid;
        float mx = -3.0e38f;
        for (int e = 0; e < NE; e++) mx = fmaxf(mx, Sl[mm * 65 + e]);
        float sum = 0.f;
        for (int e = 0; e < NE; e++) {
            float p = __expf(Sl[mm * 65 + e] - mx);
            Pl[mm * 65 + e] = p;
            sum += p;
        }
        RS[mm] = 1.0f / sum;
    }
    __syncthreads();

    #pragma unroll
    for (int qq = 0; qq < 2; qq++) {        // coalesced probs write: 512 float4
        int f = tid + 256 * qq;
        int mr = f >> 4;
        int e0 = (f & 15) * 4;
        float rs = RS[mr];
        float4 pv;
        pv.x = Pl[mr * 65 + e0 + 0] * rs;
        pv.y = Pl[mr * 65 + e0 + 1] * rs;
        pv.z = Pl[mr * 65 + e0 + 2] * rs;
        pv.w = Pl[mr * 65 + e0 + 3] * rs;
        *(float4*)&probs[(size_t)(tok0 + mr) * NE + e0] = pv;
    }

    if (tid < 32) {                          // destructive top-4, lowest-index ties
        const int mm = tid;
        float wvv[TOPK]; int idx[TOPK];
        float wsum = 0.f;
        #pragma unroll
        for (int kk = 0; kk < TOPK; ++kk) {
            float best = -3.0e38f; int bi = 0;
            for (int e = 0; e < NE; e++) {
                float v = Sl[mm * 65 + e];
                if (v > best) { best = v; bi = e; }
            }
            Sl[mm * 65 + bi] = -3.4e38f;
            float p = Pl[mm * 65 + bi];
            wvv[kk] = p; idx[kk] = bi; wsum += p;
        }
        float inv = 1.0f / wsum;
        size_t ob = (size_t)(tok0 + mm) * TOPK;
        #pragma unroll
        for (int kk = 0; kk < TOPK; kk++) {
            tkw[ob + kk] = wvv[kk] * inv * pes[idx[kk]];
            tki[ob + kk] = (float)idx[kk];   // harness reads flat buffer as float32
        }
    }
}

extern "C" void kernel_launch(void* const* d_in, const int* in_sizes, int n_in,
                              void* d_out, int out_size, void* d_ws, size_t ws_size,
                              hipStream_t stream) {
    const float* x     = (const float*)d_in[0];
    const float* w     = (const float*)d_in[1];
    const float* scale = (const float*)d_in[2];
    const float* pes   = (const float*)d_in[3];
    const int tokens = in_sizes[0] / HDIM;      // 16384

    float* probs = (float*)d_out;
    float* tkw   = probs + (size_t)tokens * NE;
    float* tki   = tkw + (size_t)tokens * TOPK;

    unsigned short* wtb = (unsigned short*)d_ws;   // 3 planes x 256 KB = 768 KB

    prep_b_kernel<<<HDIM / 32, 256, 0, stream>>>(w, scale, wtb);

    const int grid = tokens / 32;               // 512 -> 2 blocks/CU
    fused_router_kernel<<<grid, 256, 0, stream>>>(x, wtb, pes, probs, tkw, tki);
}

// Round 17
// 47.530 us; speedup vs baseline: 13.7023x; 1.2016x over previous
//
#include <hip/hip_runtime.h>
#include <cstddef>

#define HDIM 2048
#define NE 64
#define TOPK 4

typedef short bf16x8 __attribute__((ext_vector_type(8)));
typedef float f32x4 __attribute__((ext_vector_type(4)));

// Exact 3-way bf16 truncation split: a = f(h0) + f(h1) + f(h2) (24 mantissa bits).
__device__ __forceinline__ void split3(float a, unsigned short& h0,
                                       unsigned short& h1, unsigned short& h2) {
    unsigned int u = __float_as_uint(a);
    h0 = (unsigned short)(u >> 16);
    float f0 = __uint_as_float(u & 0xffff0000u);
    float r1 = a - f0;
    unsigned int v = __float_as_uint(r1);
    h1 = (unsigned short)(v >> 16);
    float f1 = __uint_as_float(v & 0xffff0000u);
    float r2 = r1 - f1;
    h2 = (unsigned short)(__float_as_uint(r2) >> 16);
}

// ---------- prepass (r16-proven, unchanged): B fragments, 3 bf16 planes ----------
// wtb[plane][s(64)][n(4)][lane(64)][j(8)]: e = 16n + (lane&15), k = 32s + 8*(lane>>4) + j
__global__ __launch_bounds__(256) void prep_b_kernel(
    const float* __restrict__ w, const float* __restrict__ scale,
    unsigned short* __restrict__ wtb)
{
    const int s = blockIdx.x;          // 0..63
    const int n = threadIdx.x >> 6;    // 0..3
    const int l = threadIdx.x & 63;
    const int e = 16 * n + (l & 15);
    const int k = 32 * s + 8 * (l >> 4);
    unsigned short h0[8], h1[8], h2[8];
    #pragma unroll
    for (int j = 0; j < 8; ++j) {
        float v = w[(size_t)e * HDIM + k + j] * scale[k + j];
        split3(v, h0[j], h1[j], h2[j]);
    }
    size_t off = ((size_t)s * 4 + n) * 512 + (size_t)l * 8;
    #pragma unroll
    for (int j = 0; j < 8; ++j) {
        wtb[off + j]          = h0[j];
        wtb[131072 + off + j] = h1[j];
        wtb[262144 + off + j] = h2[j];
    }
}

// ---------- fused: 2 A-tiles per B-frag (B bytes/CU halved), B reg-dbuf ----------
// Block = 32 tokens, 4 waves = K-quarters (kh=0..3, 16 ksteps each).
// Per wave: 32 tok x 64 exp x 512 K. Zero LDS in hot loop.
__global__ __launch_bounds__(256, 2) void fused_router_kernel(
    const float* __restrict__ x, const unsigned short* __restrict__ wtb,
    const float* __restrict__ pes,
    float* __restrict__ probs, float* __restrict__ tkw, float* __restrict__ tki)
{
    __shared__ float Sp[4][32 * 65];   // per-kh score partials
    __shared__ float SQp[4][32];       // per-kh ssq partials
    __shared__ float Sl[32 * 65];
    __shared__ float Pl[32 * 65];
    __shared__ float FN[32];
    __shared__ float RS[32];

    const int tid = threadIdx.x;
    const int kh = tid >> 6;           // K-quarter 0..3
    const int l = tid & 63;
    const int tok0 = blockIdx.x * 32;
    const int m = l & 15;              // A row / B col within tile
    const int g = l >> 4;              // k-group

    const float* xr0 = x + (size_t)(tok0 + m) * HDIM + 512 * kh + 8 * g;       // tile0
    const float* xr1 = xr0 + (size_t)16 * HDIM;                                 // tile1
    const unsigned short* wb = wtb + (size_t)(16 * kh) * 2048 + (size_t)l * 8;

    f32x4 acc0[4], acc1[4];
    #pragma unroll
    for (int n = 0; n < 4; ++n) {
        acc0[n] = (f32x4){0.f, 0.f, 0.f, 0.f};
        acc1[n] = (f32x4){0.f, 0.f, 0.f, 0.f};
    }
    float ssq0 = 0.f, ssq1 = 0.f;

    float4 Aq[2][4];
    bf16x8 Bb[2][12];

#define LOADA(buf, s) { \
        Aq[buf][0] = *(const float4*)(xr0 + 32 * (s)); \
        Aq[buf][1] = *(const float4*)(xr0 + 32 * (s) + 4); \
        Aq[buf][2] = *(const float4*)(xr1 + 32 * (s)); \
        Aq[buf][3] = *(const float4*)(xr1 + 32 * (s) + 4); }
#define LOADB(buf, s) { \
        const unsigned short* bs_ = wb + (size_t)(s) * 2048; \
        _Pragma("unroll") \
        for (int n = 0; n < 4; ++n) { \
            Bb[buf][3*n + 0] = *(const bf16x8*)(bs_ + n * 512); \
            Bb[buf][3*n + 1] = *(const bf16x8*)(bs_ + n * 512 + 131072); \
            Bb[buf][3*n + 2] = *(const bf16x8*)(bs_ + n * 512 + 262144); } }

    LOADA(0, 0);
    LOADB(0, 0);

    #pragma unroll
    for (int s = 0; s < 16; ++s) {
        const int cur = s & 1, nxt = cur ^ 1;
        if (s + 1 < 16) { LOADA(nxt, s + 1); LOADB(nxt, s + 1); }  // next kstep in flight

        float af0[8], af1[8];
        *(float4*)af0 = Aq[cur][0]; *(float4*)(af0 + 4) = Aq[cur][1];
        *(float4*)af1 = Aq[cur][2]; *(float4*)(af1 + 4) = Aq[cur][3];
        unsigned short p0[8], p1[8], p2[8], q0[8], q1[8], q2[8];
        #pragma unroll
        for (int j = 0; j < 8; ++j) {
            split3(af0[j], p0[j], p1[j], p2[j]);
            split3(af1[j], q0[j], q1[j], q2[j]);
            ssq0 = fmaf(af0[j], af0[j], ssq0);
            ssq1 = fmaf(af1[j], af1[j], ssq1);
        }
        bf16x8 a0, a1, a2, c0, c1, c2;
        #pragma unroll
        for (int j = 0; j < 8; ++j) {
            a0[j] = (short)p0[j]; a1[j] = (short)p1[j]; a2[j] = (short)p2[j];
            c0[j] = (short)q0[j]; c1[j] = (short)q1[j]; c2[j] = (short)q2[j];
        }
        #pragma unroll
        for (int n = 0; n < 4; ++n) {
            bf16x8 b0 = Bb[cur][3*n + 0];
            bf16x8 b1 = Bb[cur][3*n + 1];
            bf16x8 b2 = Bb[cur][3*n + 2];
            acc0[n] = __builtin_amdgcn_mfma_f32_16x16x32_bf16(a0, b0, acc0[n], 0, 0, 0);
            acc0[n] = __builtin_amdgcn_mfma_f32_16x16x32_bf16(a0, b1, acc0[n], 0, 0, 0);
            acc0[n] = __builtin_amdgcn_mfma_f32_16x16x32_bf16(a1, b0, acc0[n], 0, 0, 0);
            acc0[n] = __builtin_amdgcn_mfma_f32_16x16x32_bf16(a1, b1, acc0[n], 0, 0, 0);
            acc0[n] = __builtin_amdgcn_mfma_f32_16x16x32_bf16(a0, b2, acc0[n], 0, 0, 0);
            acc0[n] = __builtin_amdgcn_mfma_f32_16x16x32_bf16(a2, b0, acc0[n], 0, 0, 0);
            acc1[n] = __builtin_amdgcn_mfma_f32_16x16x32_bf16(c0, b0, acc1[n], 0, 0, 0);
            acc1[n] = __builtin_amdgcn_mfma_f32_16x16x32_bf16(c0, b1, acc1[n], 0, 0, 0);
            acc1[n] = __builtin_amdgcn_mfma_f32_16x16x32_bf16(c1, b0, acc1[n], 0, 0, 0);
            acc1[n] = __builtin_amdgcn_mfma_f32_16x16x32_bf16(c1, b1, acc1[n], 0, 0, 0);
            acc1[n] = __builtin_amdgcn_mfma_f32_16x16x32_bf16(c0, b2, acc1[n], 0, 0, 0);
            acc1[n] = __builtin_amdgcn_mfma_f32_16x16x32_bf16(c2, b0, acc1[n], 0, 0, 0);
        }
    }
#undef LOADA
#undef LOADB

    // ssq: sum the 4 k-group lanes per token (lanes differ in bits 4,5)
    ssq0 += __shfl_xor(ssq0, 16, 64);
    ssq0 += __shfl_xor(ssq0, 32, 64);
    ssq1 += __shfl_xor(ssq1, 16, 64);
    ssq1 += __shfl_xor(ssq1, 32, 64);

    // ---- stage partials; combine pairwise; fnorm ----
    #pragma unroll
    for (int n = 0; n < 4; ++n)
        #pragma unroll
        for (int r = 0; r < 4; ++r) {   // D: col=lane&15, row=4*(lane>>4)+reg [m89]
            Sp[kh][(4 * g + r) * 65 + 16 * n + m]      = acc0[n][r];
            Sp[kh][(16 + 4 * g + r) * 65 + 16 * n + m] = acc1[n][r];
        }
    if (l < 16) {
        SQp[kh][m]      = ssq0;
        SQp[kh][16 + m] = ssq1;
    }
    __syncthreads();

    if (tid < 32) {
        float st = (SQp[0][tid] + SQp[1][tid]) + (SQp[2][tid] + SQp[3][tid]);
        FN[tid] = rsqrtf(st * (1.0f / HDIM) + 1e-6f) * 0.022097086912079612f;
    }
    __syncthreads();

    #pragma unroll
    for (int qq = 0; qq < 2; qq++) {    // 512 float4: (token, expert-quad)
        int f = tid + 256 * qq;
        int mr = f >> 4;
        int e4 = (f & 15) * 4;
        float4 t0 = *(const float4*)&Sp[0][mr * 65 + e4];
        float4 t1 = *(const float4*)&Sp[1][mr * 65 + e4];
        float4 t2 = *(const float4*)&Sp[2][mr * 65 + e4];
        float4 t3 = *(const float4*)&Sp[3][mr * 65 + e4];
        float fn = FN[mr];
        Sl[mr * 65 + e4 + 0] = ((t0.x + t1.x) + (t2.x + t3.x)) * fn;
        Sl[mr * 65 + e4 + 1] = ((t0.y + t1.y) + (t2.y + t3.y)) * fn;
        Sl[mr * 65 + e4 + 2] = ((t0.z + t1.z) + (t2.z + t3.z)) * fn;
        Sl[mr * 65 + e4 + 3] = ((t0.w + t1.w) + (t2.w + t3.w)) * fn;
    }
    __syncthreads();

    // ---- proven epilogue (r16) ----
    if (tid < 32) {
        const int mm = tid;
        float mx = -3.0e38f;
        for (int e = 0; e < NE; e++) mx = fmaxf(mx, Sl[mm * 65 + e]);
        float sum = 0.f;
        for (int e = 0; e < NE; e++) {
            float p = __expf(Sl[mm * 65 + e] - mx);
            Pl[mm * 65 + e] = p;
            sum += p;
        }
        RS[mm] = 1.0f / sum;
    }
    __syncthreads();

    #pragma unroll
    for (int qq = 0; qq < 2; qq++) {    // coalesced probs write
        int f = tid + 256 * qq;
        int mr = f >> 4;
        int e0 = (f & 15) * 4;
        float rs = RS[mr];
        float4 pv;
        pv.x = Pl[mr * 65 + e0 + 0] * rs;
        pv.y = Pl[mr * 65 + e0 + 1] * rs;
        pv.z = Pl[mr * 65 + e0 + 2] * rs;
        pv.w = Pl[mr * 65 + e0 + 3] * rs;
        *(float4*)&probs[(size_t)(tok0 + mr) * NE + e0] = pv;
    }

    if (tid < 32) {                      // destructive top-4, lowest-index ties
        const int mm = tid;
        float wvv[TOPK]; int idx[TOPK];
        float wsum = 0.f;
        #pragma unroll
        for (int kk = 0; kk < TOPK; ++kk) {
            float best = -3.0e38f; int bi = 0;
            for (int e = 0; e < NE; e++) {
                float v = Sl[mm * 65 + e];
                if (v > best) { best = v; bi = e; }
            }
            Sl[mm * 65 + bi] = -3.4e38f;
            float p = Pl[mm * 65 + bi];
            wvv[kk] = p; idx[kk] = bi; wsum += p;
        }
        float inv = 1.0f / wsum;
        size_t ob = (size_t)(tok0 + mm) * TOPK;
        #pragma unroll
        for (int kk = 0; kk < TOPK; kk++) {
            tkw[ob + kk] = wvv[kk] * inv * pes[idx[kk]];
            tki[ob + kk] = (float)idx[kk];   // harness reads flat buffer as float32
        }
    }
}

extern "C" void kernel_launch(void* const* d_in, const int* in_sizes, int n_in,
                              void* d_out, int out_size, void* d_ws, size_t ws_size,
                              hipStream_t stream) {
    const float* x     = (const float*)d_in[0];
    const float* w     = (const float*)d_in[1];
    const float* scale = (const float*)d_in[2];
    const float* pes   = (const float*)d_in[3];
    const int tokens = in_sizes[0] / HDIM;      // 16384

    float* probs = (float*)d_out;
    float* tkw   = probs + (size_t)tokens * NE;
    float* tki   = tkw + (size_t)tokens * TOPK;

    unsigned short* wtb = (unsigned short*)d_ws;   // 3 planes x 256 KB = 768 KB

    prep_b_kernel<<<HDIM / 32, 256, 0, stream>>>(w, scale, wtb);

    const int grid = tokens / 32;               // 512 -> 2 blocks/CU
    fused_router_kernel<<<grid, 256, 0, stream>>>(x, wtb, pes, probs, tkw, tki);
}

// Round 18
// 44.973 us; speedup vs baseline: 14.4813x; 1.0569x over previous
//
#include <hip/hip_runtime.h>
#include <cstddef>

#define HDIM 2048
#define NE 64
#define TOPK 4

typedef short bf16x8 __attribute__((ext_vector_type(8)));
typedef float f32x4 __attribute__((ext_vector_type(4)));

// Exact 3-way bf16 truncation split: a = f(h0) + f(h1) + f(h2) (24 mantissa bits).
__device__ __forceinline__ void split3(float a, unsigned short& h0,
                                       unsigned short& h1, unsigned short& h2) {
    unsigned int u = __float_as_uint(a);
    h0 = (unsigned short)(u >> 16);
    float f0 = __uint_as_float(u & 0xffff0000u);
    float r1 = a - f0;
    unsigned int v = __float_as_uint(r1);
    h1 = (unsigned short)(v >> 16);
    float f1 = __uint_as_float(v & 0xffff0000u);
    float r2 = r1 - f1;
    h2 = (unsigned short)(__float_as_uint(r2) >> 16);
}

// ---------- prepass (r16-proven, unchanged): B fragments, 3 bf16 planes ----------
// wtb[plane][s(64)][n(4)][lane(64)][j(8)]: e = 16n + (lane&15), k = 32s + 8*(lane>>4) + j
__global__ __launch_bounds__(256) void prep_b_kernel(
    const float* __restrict__ w, const float* __restrict__ scale,
    unsigned short* __restrict__ wtb)
{
    const int s = blockIdx.x;          // 0..63
    const int n = threadIdx.x >> 6;    // 0..3
    const int l = threadIdx.x & 63;
    const int e = 16 * n + (l & 15);
    const int k = 32 * s + 8 * (l >> 4);
    unsigned short h0[8], h1[8], h2[8];
    #pragma unroll
    for (int j = 0; j < 8; ++j) {
        float v = w[(size_t)e * HDIM + k + j] * scale[k + j];
        split3(v, h0[j], h1[j], h2[j]);
    }
    size_t off = ((size_t)s * 4 + n) * 512 + (size_t)l * 8;
    #pragma unroll
    for (int j = 0; j < 8; ++j) {
        wtb[off + j]          = h0[j];
        wtb[131072 + off + j] = h1[j];
        wtb[262144 + off + j] = h2[j];
    }
}

// ---------- fused: 4 A-tiles per B-frag set (M=64/wave), A+B reg-dbuf ----------
// Block = 64 tokens, 512 thr = 8 waves = K-eighths (kh=0..7, 8 ksteps each).
// Per wave: 64 tok x 64 exp x 256 K; 96 MFMA per 12-fragment B turn. Zero LDS in hot loop.
__global__ __launch_bounds__(512, 1) void fused_router_kernel(
    const float* __restrict__ x, const unsigned short* __restrict__ wtb,
    const float* __restrict__ pes,
    float* __restrict__ probs, float* __restrict__ tkw, float* __restrict__ tki)
{
    __shared__ float Sp[8][64 * 65];   // per-kh score partials (combined in place into Sp[0])
    __shared__ float Pl[64 * 65];
    __shared__ float SQp[8][64];
    __shared__ float FN[64];
    __shared__ float RS[64];

    const int tid = threadIdx.x;
    const int kh = tid >> 6;           // K-eighth 0..7
    const int l = tid & 63;
    const int tok0 = blockIdx.x * 64;
    const int m = l & 15;              // A row / B col within tile
    const int g = l >> 4;              // k-group

    const float* xr0 = x + (size_t)(tok0 + m) * HDIM + 256 * kh + 8 * g;   // tile 0
    // tiles 1..3 at +16,+32,+48 token rows
    const unsigned short* wb = wtb + (size_t)(8 * kh) * 2048 + (size_t)l * 8;

    f32x4 acc[4][4];                   // [tile][n]
    #pragma unroll
    for (int t = 0; t < 4; ++t)
        #pragma unroll
        for (int n = 0; n < 4; ++n) acc[t][n] = (f32x4){0.f, 0.f, 0.f, 0.f};
    float ssq[4] = {0.f, 0.f, 0.f, 0.f};

    float4 Aq[2][8];                   // [buf][tile*2 + half]
    bf16x8 Bb[2][12];                  // [buf][3n+plane]

#define LOADA(buf, s) { _Pragma("unroll") \
        for (int t = 0; t < 4; ++t) { \
            Aq[buf][2*t]     = *(const float4*)(xr0 + (size_t)(16*t) * HDIM + 32 * (s)); \
            Aq[buf][2*t + 1] = *(const float4*)(xr0 + (size_t)(16*t) * HDIM + 32 * (s) + 4); } }
#define LOADB(buf, s) { \
        const unsigned short* bs_ = wb + (size_t)(s) * 2048; \
        _Pragma("unroll") \
        for (int n = 0; n < 4; ++n) { \
            Bb[buf][3*n + 0] = *(const bf16x8*)(bs_ + n * 512); \
            Bb[buf][3*n + 1] = *(const bf16x8*)(bs_ + n * 512 + 131072); \
            Bb[buf][3*n + 2] = *(const bf16x8*)(bs_ + n * 512 + 262144); } }

    LOADA(0, 0);
    LOADB(0, 0);

    #pragma unroll
    for (int s = 0; s < 8; ++s) {
        const int cur = s & 1, nxt = cur ^ 1;
        if (s + 1 < 8) { LOADB(nxt, s + 1); LOADA(nxt, s + 1); }   // next kstep in flight

        #pragma unroll
        for (int t = 0; t < 4; ++t) {  // per tile: split (transients die fast) + 24 MFMA
            float af[8];
            *(float4*)af = Aq[cur][2*t]; *(float4*)(af + 4) = Aq[cur][2*t + 1];
            unsigned short p0[8], p1[8], p2[8];
            #pragma unroll
            for (int j = 0; j < 8; ++j) {
                split3(af[j], p0[j], p1[j], p2[j]);
                ssq[t] = fmaf(af[j], af[j], ssq[t]);
            }
            bf16x8 a0, a1, a2;
            #pragma unroll
            for (int j = 0; j < 8; ++j) {
                a0[j] = (short)p0[j]; a1[j] = (short)p1[j]; a2[j] = (short)p2[j];
            }
            #pragma unroll
            for (int n = 0; n < 4; ++n) {
                bf16x8 b0 = Bb[cur][3*n + 0];
                bf16x8 b1 = Bb[cur][3*n + 1];
                bf16x8 b2 = Bb[cur][3*n + 2];
                acc[t][n] = __builtin_amdgcn_mfma_f32_16x16x32_bf16(a0, b0, acc[t][n], 0, 0, 0);
                acc[t][n] = __builtin_amdgcn_mfma_f32_16x16x32_bf16(a0, b1, acc[t][n], 0, 0, 0);
                acc[t][n] = __builtin_amdgcn_mfma_f32_16x16x32_bf16(a1, b0, acc[t][n], 0, 0, 0);
                acc[t][n] = __builtin_amdgcn_mfma_f32_16x16x32_bf16(a1, b1, acc[t][n], 0, 0, 0);
                acc[t][n] = __builtin_amdgcn_mfma_f32_16x16x32_bf16(a0, b2, acc[t][n], 0, 0, 0);
                acc[t][n] = __builtin_amdgcn_mfma_f32_16x16x32_bf16(a2, b0, acc[t][n], 0, 0, 0);
            }
        }
    }
#undef LOADA
#undef LOADB

    // ssq: sum the 4 k-group lanes per token (lanes differ in bits 4,5)
    #pragma unroll
    for (int t = 0; t < 4; ++t) {
        ssq[t] += __shfl_xor(ssq[t], 16, 64);
        ssq[t] += __shfl_xor(ssq[t], 32, 64);
    }

    // ---- stage partials ----
    #pragma unroll
    for (int t = 0; t < 4; ++t)
        #pragma unroll
        for (int n = 0; n < 4; ++n)
            #pragma unroll
            for (int r = 0; r < 4; ++r)   // D: col=lane&15, row=4*(lane>>4)+reg [m89]
                Sp[kh][(16*t + 4*g + r) * 65 + 16*n + m] = acc[t][n][r];
    if (l < 16) {
        #pragma unroll
        for (int t = 0; t < 4; ++t) SQp[kh][16*t + m] = ssq[t];
    }
    __syncthreads();

    if (tid < 64) {
        float q0 = (SQp[0][tid] + SQp[1][tid]) + (SQp[2][tid] + SQp[3][tid]);
        float q1 = (SQp[4][tid] + SQp[5][tid]) + (SQp[6][tid] + SQp[7][tid]);
        FN[tid] = rsqrtf((q0 + q1) * (1.0f / HDIM) + 1e-6f) * 0.022097086912079612f;
    }
    __syncthreads();

    #pragma unroll
    for (int qq = 0; qq < 2; qq++) {    // 1024 float4: combine 8 partials in place
        int f = tid + 512 * qq;
        int mr = f >> 4;
        int e4 = (f & 15) * 4;
        int base = mr * 65 + e4;
        float4 t0 = *(const float4*)&Sp[0][base];
        float4 t1 = *(const float4*)&Sp[1][base];
        float4 t2 = *(const float4*)&Sp[2][base];
        float4 t3 = *(const float4*)&Sp[3][base];
        float4 t4 = *(const float4*)&Sp[4][base];
        float4 t5 = *(const float4*)&Sp[5][base];
        float4 t6 = *(const float4*)&Sp[6][base];
        float4 t7 = *(const float4*)&Sp[7][base];
        float fn = FN[mr];
        float4 sv;
        sv.x = (((t0.x + t1.x) + (t2.x + t3.x)) + ((t4.x + t5.x) + (t6.x + t7.x))) * fn;
        sv.y = (((t0.y + t1.y) + (t2.y + t3.y)) + ((t4.y + t5.y) + (t6.y + t7.y))) * fn;
        sv.z = (((t0.z + t1.z) + (t2.z + t3.z)) + ((t4.z + t5.z) + (t6.z + t7.z))) * fn;
        sv.w = (((t0.w + t1.w) + (t2.w + t3.w)) + ((t4.w + t5.w) + (t6.w + t7.w))) * fn;
        *(float4*)&Sp[0][base] = sv;    // Sl == Sp[0]
    }
    __syncthreads();

    float* Sl = &Sp[0][0];

    // ---- proven epilogue (64 tokens) ----
    if (tid < 64) {
        const int mm = tid;
        float mx = -3.0e38f;
        for (int e = 0; e < NE; e++) mx = fmaxf(mx, Sl[mm * 65 + e]);
        float sum = 0.f;
        for (int e = 0; e < NE; e++) {
            float p = __expf(Sl[mm * 65 + e] - mx);
            Pl[mm * 65 + e] = p;
            sum += p;
        }
        RS[mm] = 1.0f / sum;
    }
    __syncthreads();

    #pragma unroll
    for (int qq = 0; qq < 2; qq++) {    // coalesced probs write: 1024 float4
        int f = tid + 512 * qq;
        int mr = f >> 4;
        int e0 = (f & 15) * 4;
        float rs = RS[mr];
        float4 pv;
        pv.x = Pl[mr * 65 + e0 + 0] * rs;
        pv.y = Pl[mr * 65 + e0 + 1] * rs;
        pv.z = Pl[mr * 65 + e0 + 2] * rs;
        pv.w = Pl[mr * 65 + e0 + 3] * rs;
        *(float4*)&probs[(size_t)(tok0 + mr) * NE + e0] = pv;
    }

    if (tid < 64) {                      // destructive top-4, lowest-index ties
        const int mm = tid;
        float wvv[TOPK]; int idx[TOPK];
        float wsum = 0.f;
        #pragma unroll
        for (int kk = 0; kk < TOPK; ++kk) {
            float best = -3.0e38f; int bi = 0;
            for (int e = 0; e < NE; e++) {
                float v = Sl[mm * 65 + e];
                if (v > best) { best = v; bi = e; }
            }
            Sl[mm * 65 + bi] = -3.4e38f;
            float p = Pl[mm * 65 + bi];
            wvv[kk] = p; idx[kk] = bi; wsum += p;
        }
        float inv = 1.0f / wsum;
        size_t ob = (size_t)(tok0 + mm) * TOPK;
        #pragma unroll
        for (int kk = 0; kk < TOPK; kk++) {
            tkw[ob + kk] = wvv[kk] * inv * pes[idx[kk]];
            tki[ob + kk] = (float)idx[kk];   // harness reads flat buffer as float32
        }
    }
}

extern "C" void kernel_launch(void* const* d_in, const int* in_sizes, int n_in,
                              void* d_out, int out_size, void* d_ws, size_t ws_size,
                              hipStream_t stream) {
    const float* x     = (const float*)d_in[0];
    const float* w     = (const float*)d_in[1];
    const float* scale = (const float*)d_in[2];
    const float* pes   = (const float*)d_in[3];
    const int tokens = in_sizes[0] / HDIM;      // 16384

    float* probs = (float*)d_out;
    float* tkw   = probs + (size_t)tokens * NE;
    float* tki   = tkw + (size_t)tokens * TOPK;

    unsigned short* wtb = (unsigned short*)d_ws;   // 3 planes x 256 KB = 768 KB

    prep_b_kernel<<<HDIM / 32, 256, 0, stream>>>(w, scale, wtb);

    const int grid = tokens / 64;               // 256 -> 1 block/CU
    fused_router_kernel<<<grid, 512, 0, stream>>>(x, wtb, pes, probs, tkw, tki);
}